// Round 1
// baseline (1596.532 us; speedup 1.0000x reference)
//
#include <hip/hip_runtime.h>
#include <hip/hip_bf16.h>
#include <float.h>

#define N_FEAT 6272      // B*FH*FW = 8*28*28
#define C_DIM  1024
#define M_MEM  50000
#define M_PAD  50048     // 391 * 128
#define B_IMG  8
#define IMGSZ  224
#define NTILES_M 49      // 6272/128
#define NTILES_N 391     // 50048/128

typedef __attribute__((ext_vector_type(8))) short bf16x8;
typedef __attribute__((ext_vector_type(4))) float f32x4;

// ---------- helpers ----------

__device__ inline unsigned short f2bf(float x) {
  // round-to-nearest-even fp32 -> bf16 (inputs are finite gaussians; no NaN care)
  unsigned int u = __float_as_uint(x);
  u += 0x7FFFu + ((u >> 16) & 1u);
  return (unsigned short)(u >> 16);
}

__device__ inline void gload16(const unsigned short* g, unsigned short* l) {
  // async global->LDS, 16B per lane; LDS dest = wave-uniform base + lane*16
  __builtin_amdgcn_global_load_lds((const __attribute__((address_space(1))) void*)g,
                                   (__attribute__((address_space(3))) void*)l,
                                   16, 0, 0);
}

// ---------- 1. fp32 -> bf16 conversion + row sum-of-squares ----------
// one block per (padded) row; pad rows get zeros + sq = FLT_MAX
__global__ __launch_bounds__(256) void convert_rows_kernel(
    const float* __restrict__ src, unsigned short* __restrict__ dst,
    float* __restrict__ sq, unsigned int* __restrict__ minbits, int valid_rows)
{
  int row = blockIdx.x;
  int tid = threadIdx.x;
  float s = 0.f;
  ushort4 o = make_ushort4(0, 0, 0, 0);
  if (row < valid_rows) {
    const float4* s4 = (const float4*)(src + (size_t)row * C_DIM);
    float4 v = s4[tid];
    o.x = f2bf(v.x); o.y = f2bf(v.y); o.z = f2bf(v.z); o.w = f2bf(v.w);
    s = v.x * v.x + v.y * v.y + v.z * v.z + v.w * v.w;  // exact fp32 norms
  }
  ((ushort4*)(dst + (size_t)row * C_DIM))[tid] = o;

  #pragma unroll
  for (int off = 32; off > 0; off >>= 1) s += __shfl_down(s, off, 64);
  __shared__ float red[4];
  int lane = tid & 63, wave = tid >> 6;
  if (lane == 0) red[wave] = s;
  __syncthreads();
  if (tid == 0) {
    float t = red[0] + red[1] + red[2] + red[3];
    sq[row] = (row < valid_rows) ? t : FLT_MAX;   // pad rows never win the min
    if (minbits && row < valid_rows) minbits[row] = 0x7F7FFFFFu;  // FLT_MAX bits
  }
}

// ---------- 2. bf16 MFMA "GEMM" fused with row-min + atomicMin ----------
// tile 128x128, BK=32, 4 waves in 2x2 of 64x64, m97-style global_load_lds staging.
// LDS layout per tile: 16B chunk index c = q*128 + row (q = k-octet), so fragment
// reads (16 lanes x 16B) are 256B-contiguous -> only 2-way bank aliasing (free).
__global__ __launch_bounds__(256) void gemm_min_kernel(
    const unsigned short* __restrict__ A,    // featB [6272][1024] bf16 bits
    const unsigned short* __restrict__ Bm,   // memB  [50048][1024] bf16 bits
    const float* __restrict__ f2, const float* __restrict__ m2,
    unsigned int* __restrict__ minbits)
{
  __shared__ unsigned short lds[8192];  // 16 KB: A chunks [0..511], B chunks [512..1023]
  const int tid  = threadIdx.x;
  const int wave = tid >> 6, lane = tid & 63;
  const int tileM = blockIdx.x, tileN = blockIdx.y;
  const int wr = wave >> 1, wc = wave & 1;        // 2x2 wave grid
  const int quad = lane >> 4, r16 = lane & 15;

  f32x4 acc[4][4] = {};

  // staging chunk ids: issue i in {0,1}: c = wave*128 + i*64 + lane
  const int c0 = wave * 128 + lane;
  const int c1 = c0 + 64;
  const int r0 = c0 & 127, q0 = c0 >> 7;
  const int r1 = c1 & 127, q1 = c1 >> 7;

  const unsigned short* gA0 = A  + (size_t)(tileM * 128 + r0) * C_DIM + q0 * 8;
  const unsigned short* gA1 = A  + (size_t)(tileM * 128 + r1) * C_DIM + q1 * 8;
  const unsigned short* gB0 = Bm + (size_t)(tileN * 128 + r0) * C_DIM + q0 * 8;
  const unsigned short* gB1 = Bm + (size_t)(tileN * 128 + r1) * C_DIM + q1 * 8;
  unsigned short* lA0 = lds + wave * 1024;          // wave-uniform LDS bases
  unsigned short* lA1 = lA0 + 512;
  unsigned short* lB0 = lds + 4096 + wave * 1024;
  unsigned short* lB1 = lB0 + 512;

  const bf16x8* LA = (const bf16x8*)lds;
  const bf16x8* LB = (const bf16x8*)(lds + 4096);
  const int abase = quad * 128 + wr * 64 + r16;
  const int bbase = quad * 128 + wc * 64 + r16;

  for (int kt = 0; kt < C_DIM / 32; ++kt) {
    __syncthreads();                 // prev compute done before overwrite
    gload16(gA0, lA0);
    gload16(gA1, lA1);
    gload16(gB0, lB0);
    gload16(gB1, lB1);
    gA0 += 32; gA1 += 32; gB0 += 32; gB1 += 32;
    __syncthreads();                 // vmcnt(0) drain -> LDS valid

    bf16x8 a[4], b[4];
    #pragma unroll
    for (int t = 0; t < 4; ++t) a[t] = LA[abase + t * 16];
    #pragma unroll
    for (int u = 0; u < 4; ++u) b[u] = LB[bbase + u * 16];
    #pragma unroll
    for (int t = 0; t < 4; ++t)
      #pragma unroll
      for (int u = 0; u < 4; ++u)
        acc[t][u] = __builtin_amdgcn_mfma_f32_16x16x32_bf16(a[t], b[u], acc[t][u], 0, 0, 0);
  }

  // epilogue: d2 = f2 + m2 - 2*dot, clamp >= 0, min over this block's 128 cols
  const int colbase = tileN * 128 + wc * 64 + r16;
  float m2v[4];
  #pragma unroll
  for (int u = 0; u < 4; ++u) m2v[u] = m2[colbase + u * 16];
  const int rowq = tileM * 128 + wr * 64 + quad * 4;
  #pragma unroll
  for (int t = 0; t < 4; ++t) {
    #pragma unroll
    for (int r = 0; r < 4; ++r) {
      int n = rowq + t * 16 + r;        // C/D layout: row = quad*4 + reg, col = r16
      float f2v = f2[n];
      float best = FLT_MAX;
      #pragma unroll
      for (int u = 0; u < 4; ++u) {
        float d = f2v + m2v[u] - 2.0f * acc[t][u][r];
        d = fmaxf(d, 0.0f);             // clamp-then-min == max(min,0)
        best = fminf(best, d);
      }
      best = fminf(best, __shfl_xor(best, 1, 64));
      best = fminf(best, __shfl_xor(best, 2, 64));
      best = fminf(best, __shfl_xor(best, 4, 64));
      best = fminf(best, __shfl_xor(best, 8, 64));
      if (r16 == 0) atomicMin(minbits + n, __float_as_uint(best));
    }
  }
}

// ---------- 3. sqrt + per-image max + 28x28 mask ----------
__global__ __launch_bounds__(256) void finalize_kernel(
    const unsigned int* __restrict__ minbits, float* __restrict__ m28,
    float* __restrict__ image_scores)
{
  int b = blockIdx.x, tid = threadIdx.x;
  float mx = 0.f;
  for (int i = tid; i < 784; i += 256) {
    float s = sqrtf(__uint_as_float(minbits[b * 784 + i]));
    m28[b * 784 + i] = s;
    mx = fmaxf(mx, s);
  }
  #pragma unroll
  for (int off = 32; off > 0; off >>= 1) mx = fmaxf(mx, __shfl_down(mx, off, 64));
  __shared__ float red[4];
  if ((tid & 63) == 0) red[tid >> 6] = mx;
  __syncthreads();
  if (tid == 0) image_scores[b] = fmaxf(fmaxf(red[0], red[1]), fmaxf(red[2], red[3]));
}

// ---------- 4. bilinear 28 -> 224 (half-pixel centers, edge-normalized) ----------
__global__ __launch_bounds__(256) void resize_kernel(
    const float* __restrict__ m28, float* __restrict__ out)
{
  int idx = blockIdx.x * 256 + threadIdx.x;
  if (idx >= B_IMG * IMGSZ * IMGSZ) return;
  int x = idx % IMGSZ, y = (idx / IMGSZ) % IMGSZ, b = idx / (IMGSZ * IMGSZ);
  float sy = (y + 0.5f) * 0.125f - 0.5f;
  float sx = (x + 0.5f) * 0.125f - 0.5f;
  int iy0 = (int)floorf(sy); float fy = sy - (float)iy0;
  int ix0 = (int)floorf(sx); float fx = sx - (float)ix0;
  int y0 = min(max(iy0, 0), 27), y1 = min(max(iy0 + 1, 0), 27);
  int x0 = min(max(ix0, 0), 27), x1 = min(max(ix0 + 1, 0), 27);
  const float* p = m28 + b * 784;
  float v00 = p[y0 * 28 + x0], v01 = p[y0 * 28 + x1];
  float v10 = p[y1 * 28 + x0], v11 = p[y1 * 28 + x1];
  out[idx] = (1.f - fy) * ((1.f - fx) * v00 + fx * v01) +
             fy         * ((1.f - fx) * v10 + fx * v11);
}

// ---------- 5. separable 17-tap gaussian, reflect padding ----------
__device__ inline void gauss17(float* g) {
  float s = 0.f;
  #pragma unroll
  for (int i = 0; i < 17; ++i) {
    float x = (float)(i - 8);
    g[i] = expf(-x * x * (1.0f / 32.0f));   // sigma=4 -> 2*sigma^2 = 32
    s += g[i];
  }
  float inv = 1.0f / s;
  #pragma unroll
  for (int i = 0; i < 17; ++i) g[i] *= inv;
}

__device__ inline int refl(int t) { return t < 0 ? -t : (t > 223 ? 446 - t : t); }

__global__ __launch_bounds__(256) void blur_h_kernel(
    const float* __restrict__ in, float* __restrict__ out)
{
  int idx = blockIdx.x * 256 + threadIdx.x;
  if (idx >= B_IMG * IMGSZ * IMGSZ) return;
  int x = idx % IMGSZ, y = (idx / IMGSZ) % IMGSZ, b = idx / (IMGSZ * IMGSZ);
  float g[17]; gauss17(g);
  const float* row = in + (size_t)b * IMGSZ * IMGSZ + y * IMGSZ;
  float s = 0.f;
  #pragma unroll
  for (int k = 0; k < 17; ++k) s += g[k] * row[refl(x + k - 8)];
  out[idx] = s;
}

__global__ __launch_bounds__(256) void blur_v_kernel(
    const float* __restrict__ in, float* __restrict__ out)
{
  int idx = blockIdx.x * 256 + threadIdx.x;
  if (idx >= B_IMG * IMGSZ * IMGSZ) return;
  int x = idx % IMGSZ, y = (idx / IMGSZ) % IMGSZ, b = idx / (IMGSZ * IMGSZ);
  float g[17]; gauss17(g);
  const float* img = in + (size_t)b * IMGSZ * IMGSZ;
  float s = 0.f;
  #pragma unroll
  for (int k = 0; k < 17; ++k) s += g[k] * img[refl(y + k - 8) * IMGSZ + x];
  out[idx] = s;
}

// ---------- launch ----------
extern "C" void kernel_launch(void* const* d_in, const int* in_sizes, int n_in,
                              void* d_out, int out_size, void* d_ws, size_t ws_size,
                              hipStream_t stream) {
  const float* features = (const float*)d_in[0];
  const float* memory   = (const float*)d_in[1];
  if (n_in >= 2 && in_sizes[0] > in_sizes[1]) {  // defensive: features is the smaller input
    const float* t = features; features = memory; memory = t;
  }
  float* out = (float*)d_out;
  char* ws = (char*)d_ws;

  // workspace layout (all 256B-aligned)
  unsigned short* memB  = (unsigned short*)(ws);                        // 102,498,304 B
  unsigned short* featB = (unsigned short*)(ws + 102498304);            //  12,845,056 B
  float*        f2      = (float*)(ws + 115343360);                     //      25,088 B
  float*        m2      = (float*)(ws + 115368448);                     //     200,192 B
  unsigned int* minb    = (unsigned int*)(ws + 115568640);              //      25,088 B
  float*        m28     = (float*)(ws + 115593728);                     //      25,088 B
  float*        rsz     = (float*)(ws + 115618816);                     //   1,605,632 B
  float*        tmp     = (float*)(ws + 117224448);                     //   1,605,632 B

  convert_rows_kernel<<<M_PAD, 256, 0, stream>>>(memory, memB, m2, nullptr, M_MEM);
  convert_rows_kernel<<<N_FEAT, 256, 0, stream>>>(features, featB, f2, minb, N_FEAT);

  dim3 grid(NTILES_M, NTILES_N);  // x = row tile (fast) -> consecutive blocks share B tile
  gemm_min_kernel<<<grid, 256, 0, stream>>>(featB, memB, f2, m2, minb);

  finalize_kernel<<<B_IMG, 256, 0, stream>>>(minb, m28, out);
  resize_kernel<<<(B_IMG * IMGSZ * IMGSZ) / 256, 256, 0, stream>>>(m28, rsz);
  blur_h_kernel<<<(B_IMG * IMGSZ * IMGSZ) / 256, 256, 0, stream>>>(rsz, tmp);
  blur_v_kernel<<<(B_IMG * IMGSZ * IMGSZ) / 256, 256, 0, stream>>>(tmp, out + 8);
}